// Round 4
// baseline (1772.796 us; speedup 1.0000x reference)
//
#include <hip/hip_runtime.h>
#include <hip/hip_bf16.h>
#include <math.h>

// B=8, H=64, W=64, C=512 -> rows M = 32768; T=77, HH=8, DH=64, TOP_M=3
#define MROWS 32768
#define CDIM  512
#define TTOK  77
#define BTOK  616
#define NTOK  16777216

typedef __attribute__((ext_vector_type(8))) short short8;
typedef __attribute__((ext_vector_type(4))) float float4v;

__device__ __forceinline__ float ldin(const void* p, size_t i, int isf32) {
  return isf32 ? ((const float*)p)[i]
               : __bfloat162float(((const __hip_bfloat16*)p)[i]);
}

// async global->LDS, 16B per lane; LDS dest = uniform base + lane*16
__device__ __forceinline__ void gload16(const void* g, void* l) {
  __builtin_amdgcn_global_load_lds((const __attribute__((address_space(1))) unsigned int*)g,
                                   (__attribute__((address_space(3))) unsigned int*)l,
                                   16, 0, 0);
}

__device__ __forceinline__ float wave_sum(float v) {
#pragma unroll
  for (int off = 32; off > 0; off >>= 1) v += __shfl_xor(v, off, 64);
  return v;
}
__device__ __forceinline__ float wave_max(float v) {
#pragma unroll
  for (int off = 32; off > 0; off >>= 1) v = fmaxf(v, __shfl_xor(v, off, 64));
  return v;
}
__device__ __forceinline__ float block_sum256(float v) {
  __shared__ float red[4];
  int lane = threadIdx.x & 63, wid = threadIdx.x >> 6;
  float s = wave_sum(v);
  if (lane == 0) red[wid] = s;
  __syncthreads();
  s = red[0] + red[1] + red[2] + red[3];
  __syncthreads();
  return s;
}

// dtype detect (proven): 1 => fp32 inputs, 0 => bf16 inputs
__global__ __launch_bounds__(256) void detect_kernel(const unsigned int* __restrict__ t,
                                                     int* __restrict__ flag) {
  int insane = 0;
  for (int i = threadIdx.x; i < 4096; i += 256) {
    unsigned int lo = t[i] & 0xFFFFu;
    int e = (int)((lo >> 7) & 0xFFu);
    int sane = (lo == 0u) || (e >= 87 && e <= 147);
    insane += 1 - sane;
  }
  float tot = block_sum256((float)insane);
  if (threadIdx.x == 0) flag[0] = (tot > 1024.0f) ? 1 : 0;
}

// fused small-parameter convert: one block per segment
struct PC { const void* src; float* dst; int n; };
struct PCTab { PC e[14]; };
__global__ __launch_bounds__(256) void cvt_params_kernel(PCTab t, const int* __restrict__ flag) {
  int f = *flag;
  PC p = t.e[blockIdx.x];
  for (int i = threadIdx.x; i < p.n; i += 256) p.dst[i] = ldin(p.src, i, f);
}

// weight transpose+convert: in (KxN, raw dtype) -> out bf16 (NxK)
__global__ __launch_bounds__(256) void tcvt_kernel(const void* __restrict__ in,
                                                   __hip_bfloat16* __restrict__ out,
                                                   int K, int N, const int* __restrict__ flag) {
  __shared__ float tile[32][33];
  int tx = threadIdx.x & 31, ty = threadIdx.x >> 5;   // 32 x 8
  int k0 = blockIdx.y * 32, n0 = blockIdx.x * 32;
  int f = *flag;
#pragma unroll
  for (int r = 0; r < 4; ++r) {
    int k = k0 + ty + r * 8;
    tile[ty + r * 8][tx] = ldin(in, (size_t)k * N + n0 + tx, f);
  }
  __syncthreads();
#pragma unroll
  for (int r = 0; r < 4; ++r) {
    int n = n0 + ty + r * 8;
    out[(size_t)n * K + k0 + tx] = __float2bfloat16(tile[tx][ty + r * 8]);
  }
}

// pad mask straight from raw text
__global__ __launch_bounds__(256) void pad_kernel(const void* __restrict__ text,
                                                  float* __restrict__ pad,
                                                  const int* __restrict__ flag) {
  int row = blockIdx.x;
  size_t base = (size_t)row * CDIM;
  int tid = threadIdx.x;
  int f = *flag;
  float s = fabsf(ldin(text, base + tid, f)) + fabsf(ldin(text, base + 256 + tid, f));
  float tot = block_sum256(s);
  if (tid == 0) pad[row] = (tot <= 1e-6f) ? 1.0f : 0.0f;
}

// LayerNorm over C=512 (raw flag-dtype input) -> bf16 out
__global__ __launch_bounds__(256) void ln_kernel(const void* __restrict__ in,
                                                 const float* __restrict__ w,
                                                 const float* __restrict__ b,
                                                 __hip_bfloat16* __restrict__ out,
                                                 const int* __restrict__ flag) {
  int row = blockIdx.x;
  size_t base = (size_t)row * CDIM;
  int tid = threadIdx.x;
  int f = *flag;
  float v0 = ldin(in, base + tid, f);
  float v1 = ldin(in, base + 256 + tid, f);
  float tot = block_sum256(v0 + v1);
  float mu = tot * (1.0f / 512.0f);
  float d0 = v0 - mu, d1 = v1 - mu;
  float sqs = block_sum256(d0 * d0 + d1 * d1);
  float rs = rsqrtf(sqs * (1.0f / 512.0f) + 1e-5f);
  out[base + tid]       = __float2bfloat16(d0 * rs * w[tid]       + b[tid]);
  out[base + 256 + tid] = __float2bfloat16(d1 * rs * w[256 + tid] + b[256 + tid]);
}

__global__ __launch_bounds__(256) void rownorm_kernel(float* __restrict__ x) {
  int row = blockIdx.x;
  size_t base = (size_t)row * CDIM;
  int tid = threadIdx.x;
  float v0 = x[base + tid], v1 = x[base + 256 + tid];
  float sq = block_sum256(v0 * v0 + v1 * v1);
  float inv = 1.0f / fmaxf(sqrtf(sq), 1e-6f);
  x[base + tid] = v0 * inv;
  x[base + 256 + tid] = v1 * inv;
}

// g = alpha * sigmoid(x.Wg + bg) * (conf>=0.35); x bf16
__global__ __launch_bounds__(256) void gate_kernel(const __hip_bfloat16* __restrict__ x,
                                                   const float* __restrict__ Wg,
                                                   const float* __restrict__ bg,
                                                   const float* __restrict__ confh,
                                                   const float* __restrict__ alpha_p,
                                                   float* __restrict__ g) {
  int lane = threadIdx.x & 63, wid = threadIdx.x >> 6;
  int row = blockIdx.x * 4 + wid;
  size_t base = (size_t)row * CDIM;
  float acc = 0.0f;
#pragma unroll
  for (int j = 0; j < 8; ++j)
    acc += __bfloat162float(x[base + j * 64 + lane]) * Wg[j * 64 + lane];
  acc = wave_sum(acc);
  float cs = (lane < 8) ? confh[(size_t)lane * MROWS + row] : 0.0f;
  cs = wave_sum(cs);
  if (lane == 0) {
    float gate = 1.0f / (1.0f + expf(-(acc + bg[0])));
    float byp = (cs * 0.125f >= 0.35f) ? 1.0f : 0.0f;
    g[row] = alpha_p[0] * gate * byp;
  }
}

// fused: y = x + g*proj (fp32 back into proj, needed as MLP residual);
//        y2 = LN(y) -> bf16
__global__ __launch_bounds__(256) void combine_ln_kernel(const __hip_bfloat16* __restrict__ x,
                                                         float* __restrict__ proj,
                                                         const float* __restrict__ g,
                                                         const float* __restrict__ w,
                                                         const float* __restrict__ b,
                                                         __hip_bfloat16* __restrict__ y2) {
  int row = blockIdx.x;
  size_t base = (size_t)row * CDIM;
  int tid = threadIdx.x;
  float gv = g[row];
  float v0 = __bfloat162float(x[base + tid])       + gv * proj[base + tid];
  float v1 = __bfloat162float(x[base + 256 + tid]) + gv * proj[base + 256 + tid];
  proj[base + tid] = v0;
  proj[base + 256 + tid] = v1;
  float tot = block_sum256(v0 + v1);
  float mu = tot * (1.0f / 512.0f);
  float d0 = v0 - mu, d1 = v1 - mu;
  float sqs = block_sum256(d0 * d0 + d1 * d1);
  float rs = rsqrtf(sqs * (1.0f / 512.0f) + 1e-5f);
  y2[base + tid]       = __float2bfloat16(d0 * rs * w[tid]       + b[tid]);
  y2[base + 256 + tid] = __float2bfloat16(d1 * rs * w[256 + tid] + b[256 + tid]);
}

// ---------------- attention: 8-row register blocking ----------------
__global__ __launch_bounds__(256) void attn_kernel(const float* __restrict__ qn,
                                                   const float* __restrict__ kn,
                                                   const float* __restrict__ vf,
                                                   const float* __restrict__ pad,
                                                   const float* __restrict__ ls_p,
                                                   __hip_bfloat16* __restrict__ aligned,
                                                   float* __restrict__ confh) {
  __shared__ float kt[TTOK * 68];
  __shared__ float vt[TTOK * 68];
  __shared__ float qt[32 * 64];
  int tid = threadIdx.x;
  int lane = tid & 63, wid = tid >> 6;
  int blk = blockIdx.x;
  int nchunk = blk & 127;
  int bh = blk >> 7;
  int h = bh & 7, b = bh >> 3;

  for (int idx = tid; idx < TTOK * 64; idx += 256) {
    int t = idx >> 6, d = idx & 63;
    size_t src = ((size_t)(b * TTOK + t)) * CDIM + h * 64 + d;
    kt[t * 68 + d] = kn[src];
    vt[t * 68 + d] = vf[src];
  }
  for (int idx = tid; idx < 32 * 64; idx += 256) {
    int nl = idx >> 6, d = idx & 63;
    qt[idx] = qn[((size_t)(b * 4096 + nchunk * 32 + nl)) * CDIM + h * 64 + d];
  }
  __syncthreads();

  float ls = fminf(fmaxf(ls_p[0], -2.0f), 2.0f);
  float scale = expf(ls) * 0.125f;
  const float NEGINF = -__builtin_inff();
  float pv0 = pad[b * TTOK + lane];
  int t1ok = (lane + 64 < TTOK);
  float pv1 = t1ok ? pad[b * TTOK + lane + 64] : 1.0f;
  int t1 = t1ok ? lane + 64 : 0;

  // QK^T for all 8 rows of this wave in one K-fragment pass
  float s0[8], s1[8];
#pragma unroll
  for (int r = 0; r < 8; ++r) { s0[r] = 0.0f; s1[r] = 0.0f; }
  {
    const float4* k0p = (const float4*)&kt[lane * 68];
    const float4* k1p = (const float4*)&kt[t1 * 68];
    const float4* qtp = (const float4*)&qt[wid * 8 * 64];
#pragma unroll
    for (int dg = 0; dg < 16; ++dg) {
      float4 ka = k0p[dg];
      float4 kb = k1p[dg];
#pragma unroll
      for (int r = 0; r < 8; ++r) {
        float4 qq = qtp[r * 16 + dg];   // wave-uniform broadcast read
        s0[r] += qq.x * ka.x + qq.y * ka.y + qq.z * ka.z + qq.w * ka.w;
        s1[r] += qq.x * kb.x + qq.y * kb.y + qq.z * kb.z + qq.w * kb.w;
      }
    }
  }

#pragma unroll 1
  for (int i = 0; i < 8; ++i) {
    int n = nchunk * 32 + wid * 8 + i;
    size_t qbase = ((size_t)(b * 4096 + n)) * CDIM + h * 64;
    float v0 = (pv0 > 0.0f) ? NEGINF : s0[i] * scale;
    float v1 = (!t1ok || pv1 > 0.0f) ? NEGINF : s1[i] * scale;

    float m1 = wave_max(fmaxf(v0, v1));
    float a0 = 0.0f, a1 = 0.0f, conf_h = 0.0f;
    unsigned long long km0 = 0ull, km1 = 0ull;
    if (m1 != NEGINF) {
      int c1 = __popcll(__ballot(v0 >= m1)) + __popcll(__ballot(v1 >= m1));
      float thr;
      if (c1 >= 3) thr = m1;
      else {
        float m2 = wave_max(fmaxf(v0 < m1 ? v0 : NEGINF, v1 < m1 ? v1 : NEGINF));
        int c2 = __popcll(__ballot(v0 >= m2)) + __popcll(__ballot(v1 >= m2));
        if (c2 >= 3) thr = m2;
        else thr = wave_max(fmaxf(v0 < m2 ? v0 : NEGINF, v1 < m2 ? v1 : NEGINF));
      }
      float p0 = (v0 >= thr) ? expf(v0 - m1) : 0.0f;
      float p1 = (v1 >= thr) ? expf(v1 - m1) : 0.0f;
      float sum = wave_sum(p0 + p1);
      a0 = p0 / sum; a1 = p1 / sum;
      float sum2 = wave_sum(a0 + a1);
      float rden = 1.0f / fmaxf(sum2, 1e-6f);
      a0 *= rden; a1 *= rden;
      km0 = __ballot(a0 > 0.0f);
      km1 = __ballot(a1 > 0.0f);
      int cnt = __popcll(km0) + __popcll(km1);
      float maxp = wave_max(fmaxf(a0, a1));
      float es = wave_sum((a0 > 0.0f ? -a0 * logf(a0) : 0.0f) +
                          (a1 > 0.0f ? -a1 * logf(a1) : 0.0f));
      es += (float)(TTOK - cnt) * 1.8420680743952367e-7f;
      float teff = fmaxf((float)cnt, 2.0f);
      float ent = fmaxf(es / logf(teff), 0.0f);
      conf_h = fminf(fmaxf(maxp * (1.0f - ent), 0.0f), 1.0f);
    }
    if (lane == 0) confh[(size_t)h * MROWS + b * 4096 + n] = conf_h;

    float acc = 0.0f;
    unsigned long long m = km0;
    while (m) {
      int t = __builtin_ctzll(m);
      acc += __shfl(a0, t, 64) * vt[t * 68 + lane];
      m &= m - 1;
    }
    m = km1;
    while (m) {
      int t = __builtin_ctzll(m);
      acc += __shfl(a1, t, 64) * vt[(t + 64) * 68 + lane];
      m &= m - 1;
    }
    aligned[qbase + lane] = __float2bfloat16(acc);
  }
}

// ---------------- bf16 MFMA GEMM, m97-style global_load_lds staging ----------------
// C = A(MxK bf16) @ BT^T + bias; BT is NxK bf16. M%128==0, N%128==0, K%32==0.
// mode 0: out bf16; mode 1: out fp32; mode 2: out d_out (fp32 if *flag else bf16) at ooff.
__global__ __launch_bounds__(256) void mfma_gemm(const short* __restrict__ A,
                                                 const short* __restrict__ BT,
                                                 const float* __restrict__ bias,
                                                 void* __restrict__ outp,
                                                 int mode, size_t ooff,
                                                 const int* __restrict__ flag,
                                                 const float* __restrict__ resid,
                                                 int M, int N, int K, int act) {
  __shared__ short As[128 * 32];   // unpadded: required by global_load_lds lane mapping
  __shared__ short Bs[128 * 32];
  int tid = threadIdx.x;
  int lane = tid & 63, w = tid >> 6;
  int wr = w >> 1, wc = w & 1;
  int bm = blockIdx.y * 128, bn = blockIdx.x * 128;
  float4v acc[4][4];
#pragma unroll
  for (int i = 0; i < 4; ++i)
#pragma unroll
    for (int j = 0; j < 4; ++j) acc[i][j] = (float4v){0.f, 0.f, 0.f, 0.f};

  // staging: wave w covers rows [w*32, w*32+32); inst j covers 16 rows.
  // lane i -> row w*32 + j*16 + i/4, shorts [ (i%4)*8 , +8 )
  int srow = w * 32 + (lane >> 2);
  int scol = (lane & 3) * 8;
  const short* Ag0 = A + (size_t)(bm + srow) * K + scol;
  const short* Ag1 = A + (size_t)(bm + srow + 16) * K + scol;
  const short* Bg0 = BT + (size_t)(bn + srow) * K + scol;
  const short* Bg1 = BT + (size_t)(bn + srow + 16) * K + scol;
  short* Al0 = As + w * 1024;          // (w*32 rows)*32 shorts
  short* Al1 = As + w * 1024 + 512;    // +16 rows
  short* Bl0 = Bs + w * 1024;
  short* Bl1 = Bs + w * 1024 + 512;

  int m0 = wr * 64 + (lane & 15);
  int n0 = wc * 64 + (lane & 15);
  int kg = (lane >> 4) * 8;

  for (int k0 = 0; k0 < K; k0 += 32) {
    __syncthreads();                    // prev fragments consumed
    gload16(Ag0 + k0, Al0);
    gload16(Ag1 + k0, Al1);
    gload16(Bg0 + k0, Bl0);
    gload16(Bg1 + k0, Bl1);
    __syncthreads();                    // vmcnt drained here by compiler
    short8 af[4], bf[4];
#pragma unroll
    for (int mi = 0; mi < 4; ++mi) af[mi] = *(const short8*)&As[(m0 + mi * 16) * 32 + kg];
#pragma unroll
    for (int ni = 0; ni < 4; ++ni) bf[ni] = *(const short8*)&Bs[(n0 + ni * 16) * 32 + kg];
#pragma unroll
    for (int mi = 0; mi < 4; ++mi)
#pragma unroll
      for (int ni = 0; ni < 4; ++ni)
        acc[mi][ni] = __builtin_amdgcn_mfma_f32_16x16x32_bf16(af[mi], bf[ni], acc[mi][ni], 0, 0, 0);
  }

  int outf32 = (mode == 2) ? *flag : 0;
#pragma unroll
  for (int mi = 0; mi < 4; ++mi) {
#pragma unroll
    for (int ni = 0; ni < 4; ++ni) {
#pragma unroll
      for (int r = 0; r < 4; ++r) {
        int gr = bm + wr * 64 + mi * 16 + (lane >> 4) * 4 + r;
        int gc = bn + wc * 64 + ni * 16 + (lane & 15);
        float v = acc[mi][ni][r] + bias[gc];
        if (act == 1) v = 0.5f * v * (1.0f + erff(v * 0.70710678118654752f));
        if (resid) v += resid[(size_t)gr * N + gc];
        size_t oi = (size_t)gr * N + gc;
        if (mode == 0)      ((__hip_bfloat16*)outp)[oi] = __float2bfloat16(v);
        else if (mode == 1) ((float*)outp)[oi] = v;
        else {
          if (outf32) ((float*)outp)[ooff + oi] = v;
          else        ((__hip_bfloat16*)outp)[ooff + oi] = __float2bfloat16(v);
        }
      }
    }
  }
}

// ---------------- fused k & v fp32 GEMM (raw inputs), M=616 ----------------
__global__ __launch_bounds__(256) void kv_gemm(const void* __restrict__ text,
                                               const void* __restrict__ Wk,
                                               const void* __restrict__ Wv,
                                               const float* __restrict__ bk,
                                               const float* __restrict__ bv,
                                               float* __restrict__ kf,
                                               float* __restrict__ vf,
                                               const int* __restrict__ flag) {
  __shared__ float As[16][128];
  __shared__ float Bs[16][128];
  int f = *flag;
  int isv = blockIdx.x >> 2;
  int bn = (blockIdx.x & 3) * 128;
  int bm = blockIdx.y * 128;
  const void* B = isv ? Wv : Wk;
  const float* bias = isv ? bv : bk;
  float* C = isv ? vf : kf;
  int tid = threadIdx.x;
  int tx = tid & 15, ty = tid >> 4;
  float acc[8][8] = {};
  for (int k0 = 0; k0 < 512; k0 += 16) {
#pragma unroll
    for (int r = 0; r < 8; ++r) {
      int idx = tid + r * 256;
      int row = idx >> 4, kk = idx & 15;
      int gr = bm + row;
      As[kk][row] = (gr < BTOK) ? ldin(text, (size_t)gr * 512 + k0 + kk, f) : 0.0f;
    }
#pragma unroll
    for (int r = 0; r < 8; ++r) {
      int idx = tid + r * 256;
      int kk = idx >> 7, col = idx & 127;
      Bs[kk][col] = ldin(B, (size_t)(k0 + kk) * 512 + bn + col, f);
    }
    __syncthreads();
#pragma unroll
    for (int kk = 0; kk < 16; ++kk) {
      float ra[8], rb[8];
#pragma unroll
      for (int i = 0; i < 8; ++i) ra[i] = As[kk][ty * 8 + i];
#pragma unroll
      for (int j = 0; j < 8; ++j) rb[j] = Bs[kk][tx * 8 + j];
#pragma unroll
      for (int i = 0; i < 8; ++i)
#pragma unroll
        for (int j = 0; j < 8; ++j) acc[i][j] += ra[i] * rb[j];
    }
    __syncthreads();
  }
#pragma unroll
  for (int i = 0; i < 8; ++i) {
    int gr = bm + ty * 8 + i;
    if (gr >= BTOK) continue;
#pragma unroll
    for (int j = 0; j < 8; ++j) {
      int gc = bn + tx * 8 + j;
      C[(size_t)gr * 512 + gc] = acc[i][j] + bias[gc];
    }
  }
}

extern "C" void kernel_launch(void* const* d_in, const int* in_sizes, int n_in,
                              void* d_out, int out_size, void* d_ws, size_t ws_size,
                              hipStream_t stream) {
  const void* visual = d_in[0];
  const void* text   = d_in[1];

  char* wsb = (char*)d_ws;
  size_t off = 0;
  auto alloc = [&](size_t bytes) { char* p = wsb + off; off += (bytes + 63) & ~63ull; return p; };

  float* qpy  = (float*)alloc((size_t)NTOK * 4);                    // q -> proj -> y
  __hip_bfloat16* xb2 = (__hip_bfloat16*)alloc((size_t)NTOK * 2);   // x -> y2
  __hip_bfloat16* alb = (__hip_bfloat16*)alloc((size_t)NTOK * 2);   // aligned
  __hip_bfloat16* h1b = (__hip_bfloat16*)alloc((size_t)8192 * 2048 * 2);
  float* kfb  = (float*)alloc((size_t)BTOK * CDIM * 4);
  float* vfb  = (float*)alloc((size_t)BTOK * CDIM * 4);
  float* padb = (float*)alloc(BTOK * 4);
  float* confh = (float*)alloc((size_t)8 * MROWS * 4);
  float* gbuf  = (float*)alloc(MROWS * 4);
  float* n1w = (float*)alloc(512 * 4);  float* n1b = (float*)alloc(512 * 4);
  float* n2w = (float*)alloc(512 * 4);  float* n2b = (float*)alloc(512 * 4);
  float* bq  = (float*)alloc(512 * 4);  float* bk = (float*)alloc(512 * 4);
  float* bv  = (float*)alloc(512 * 4);  float* bo = (float*)alloc(512 * 4);
  float* Wgf = (float*)alloc(512 * 4);  float* bg = (float*)alloc(16);
  float* lsb = (float*)alloc(16);
  float* b1  = (float*)alloc(2048 * 4); float* b2 = (float*)alloc(512 * 4);
  float* alp = (float*)alloc(16);
  __hip_bfloat16* WqT = (__hip_bfloat16*)alloc((size_t)262144 * 2);
  __hip_bfloat16* WoT = (__hip_bfloat16*)alloc((size_t)262144 * 2);
  __hip_bfloat16* W1T = (__hip_bfloat16*)alloc((size_t)1048576 * 2);
  __hip_bfloat16* W2T = (__hip_bfloat16*)alloc((size_t)1048576 * 2);
  int* flag = (int*)alloc(16);

  detect_kernel<<<1, 256, 0, stream>>>((const unsigned int*)text, flag);

  PCTab tab = {{
    {d_in[2], n1w, 512}, {d_in[3], n1b, 512}, {d_in[4], n2w, 512}, {d_in[5], n2b, 512},
    {d_in[7], bq, 512},  {d_in[9], bk, 512},  {d_in[11], bv, 512}, {d_in[13], bo, 512},
    {d_in[14], Wgf, 512}, {d_in[15], bg, 1},  {d_in[16], lsb, 1},
    {d_in[18], b1, 2048}, {d_in[20], b2, 512}, {d_in[21], alp, 1},
  }};
  cvt_params_kernel<<<14, 256, 0, stream>>>(tab, flag);

  tcvt_kernel<<<dim3(16, 16), 256, 0, stream>>>(d_in[6],  WqT, 512, 512, flag);
  tcvt_kernel<<<dim3(16, 16), 256, 0, stream>>>(d_in[12], WoT, 512, 512, flag);
  tcvt_kernel<<<dim3(64, 16), 256, 0, stream>>>(d_in[17], W1T, 512, 2048, flag);
  tcvt_kernel<<<dim3(16, 64), 256, 0, stream>>>(d_in[19], W2T, 2048, 512, flag);

  pad_kernel<<<BTOK, 256, 0, stream>>>(text, padb, flag);
  ln_kernel<<<MROWS, 256, 0, stream>>>(visual, n1w, n1b, xb2, flag);

  mfma_gemm<<<dim3(4, 256), 256, 0, stream>>>((const short*)xb2, (const short*)WqT, bq,
                                              qpy, 1, 0, flag, nullptr, MROWS, 512, 512, 0);
  kv_gemm<<<dim3(8, 5), 256, 0, stream>>>(text, d_in[8], d_in[10], bk, bv, kfb, vfb, flag);
  rownorm_kernel<<<MROWS, 256, 0, stream>>>(qpy);
  rownorm_kernel<<<BTOK, 256, 0, stream>>>(kfb);

  attn_kernel<<<8 * 8 * 128, 256, 0, stream>>>(qpy, kfb, vfb, padb, lsb, alb, confh);

  mfma_gemm<<<dim3(4, 256), 256, 0, stream>>>((const short*)alb, (const short*)WoT, bo,
                                              qpy, 1, 0, flag, nullptr, MROWS, 512, 512, 0);
  gate_kernel<<<MROWS / 4, 256, 0, stream>>>(xb2, Wgf, bg, confh, alp, gbuf);
  combine_ln_kernel<<<MROWS, 256, 0, stream>>>(xb2, qpy, gbuf, n2w, n2b, xb2);

  for (int c = 0; c < 4; ++c) {
    const short* ychunk = (const short*)(xb2 + (size_t)c * 8192 * CDIM);
    const float* yres   = qpy + (size_t)c * 8192 * CDIM;
    mfma_gemm<<<dim3(16, 64), 256, 0, stream>>>(ychunk, (const short*)W1T, b1,
                                                h1b, 0, 0, flag, nullptr, 8192, 2048, 512, 1);
    mfma_gemm<<<dim3(4, 64), 256, 0, stream>>>((const short*)h1b, (const short*)W2T, b2,
                                               d_out, 2, (size_t)c * 8192 * CDIM, flag, yres,
                                               8192, 512, 2048, 0);
  }
}

// Round 5
// 1168.936 us; speedup vs baseline: 1.5166x; 1.5166x over previous
//
#include <hip/hip_runtime.h>
#include <hip/hip_bf16.h>
#include <math.h>

// B=8, H=64, W=64, C=512 -> rows M = 32768; T=77, HH=8, DH=64, TOP_M=3
#define MROWS 32768
#define CDIM  512
#define TTOK  77
#define BTOK  616
#define NTOK  16777216

typedef __attribute__((ext_vector_type(8))) short short8;
typedef __attribute__((ext_vector_type(4))) float float4v;

__device__ __forceinline__ float ldin(const void* p, size_t i, int isf32) {
  return isf32 ? ((const float*)p)[i]
               : __bfloat162float(((const __hip_bfloat16*)p)[i]);
}

// async global->LDS, 16B per lane; LDS dest = uniform base + lane*16
__device__ __forceinline__ void gload16(const void* g, void* l) {
  __builtin_amdgcn_global_load_lds((const __attribute__((address_space(1))) unsigned int*)g,
                                   (__attribute__((address_space(3))) unsigned int*)l,
                                   16, 0, 0);
}

__device__ __forceinline__ float wave_sum(float v) {
#pragma unroll
  for (int off = 32; off > 0; off >>= 1) v += __shfl_xor(v, off, 64);
  return v;
}
__device__ __forceinline__ float wave_max(float v) {
#pragma unroll
  for (int off = 32; off > 0; off >>= 1) v = fmaxf(v, __shfl_xor(v, off, 64));
  return v;
}
__device__ __forceinline__ float block_sum256(float v) {
  __shared__ float red[4];
  int lane = threadIdx.x & 63, wid = threadIdx.x >> 6;
  float s = wave_sum(v);
  if (lane == 0) red[wid] = s;
  __syncthreads();
  s = red[0] + red[1] + red[2] + red[3];
  __syncthreads();
  return s;
}

// dtype detect (proven): 1 => fp32 inputs, 0 => bf16 inputs
__global__ __launch_bounds__(256) void detect_kernel(const unsigned int* __restrict__ t,
                                                     int* __restrict__ flag) {
  int insane = 0;
  for (int i = threadIdx.x; i < 4096; i += 256) {
    unsigned int lo = t[i] & 0xFFFFu;
    int e = (int)((lo >> 7) & 0xFFu);
    int sane = (lo == 0u) || (e >= 87 && e <= 147);
    insane += 1 - sane;
  }
  float tot = block_sum256((float)insane);
  if (threadIdx.x == 0) flag[0] = (tot > 1024.0f) ? 1 : 0;
}

// fused small-parameter convert: one block per segment
struct PC { const void* src; float* dst; int n; };
struct PCTab { PC e[14]; };
__global__ __launch_bounds__(256) void cvt_params_kernel(PCTab t, const int* __restrict__ flag) {
  int f = *flag;
  PC p = t.e[blockIdx.x];
  for (int i = threadIdx.x; i < p.n; i += 256) p.dst[i] = ldin(p.src, i, f);
}

// weight transpose+convert: in (KxN, raw dtype) -> out bf16 (NxK)
__global__ __launch_bounds__(256) void tcvt_kernel(const void* __restrict__ in,
                                                   __hip_bfloat16* __restrict__ out,
                                                   int K, int N, const int* __restrict__ flag) {
  __shared__ float tile[32][33];
  int tx = threadIdx.x & 31, ty = threadIdx.x >> 5;   // 32 x 8
  int k0 = blockIdx.y * 32, n0 = blockIdx.x * 32;
  int f = *flag;
#pragma unroll
  for (int r = 0; r < 4; ++r) {
    int k = k0 + ty + r * 8;
    tile[ty + r * 8][tx] = ldin(in, (size_t)k * N + n0 + tx, f);
  }
  __syncthreads();
#pragma unroll
  for (int r = 0; r < 4; ++r) {
    int n = n0 + ty + r * 8;
    out[(size_t)n * K + k0 + tx] = __float2bfloat16(tile[tx][ty + r * 8]);
  }
}

// pad mask straight from raw text
__global__ __launch_bounds__(256) void pad_kernel(const void* __restrict__ text,
                                                  float* __restrict__ pad,
                                                  const int* __restrict__ flag) {
  int row = blockIdx.x;
  size_t base = (size_t)row * CDIM;
  int tid = threadIdx.x;
  int f = *flag;
  float s = fabsf(ldin(text, base + tid, f)) + fabsf(ldin(text, base + 256 + tid, f));
  float tot = block_sum256(s);
  if (tid == 0) pad[row] = (tot <= 1e-6f) ? 1.0f : 0.0f;
}

// LayerNorm over C=512 (raw flag-dtype input) -> bf16 out
__global__ __launch_bounds__(256) void ln_kernel(const void* __restrict__ in,
                                                 const float* __restrict__ w,
                                                 const float* __restrict__ b,
                                                 __hip_bfloat16* __restrict__ out,
                                                 const int* __restrict__ flag) {
  int row = blockIdx.x;
  size_t base = (size_t)row * CDIM;
  int tid = threadIdx.x;
  int f = *flag;
  float v0 = ldin(in, base + tid, f);
  float v1 = ldin(in, base + 256 + tid, f);
  float tot = block_sum256(v0 + v1);
  float mu = tot * (1.0f / 512.0f);
  float d0 = v0 - mu, d1 = v1 - mu;
  float sqs = block_sum256(d0 * d0 + d1 * d1);
  float rs = rsqrtf(sqs * (1.0f / 512.0f) + 1e-5f);
  out[base + tid]       = __float2bfloat16(d0 * rs * w[tid]       + b[tid]);
  out[base + 256 + tid] = __float2bfloat16(d1 * rs * w[256 + tid] + b[256 + tid]);
}

__global__ __launch_bounds__(256) void rownorm_kernel(float* __restrict__ x) {
  int row = blockIdx.x;
  size_t base = (size_t)row * CDIM;
  int tid = threadIdx.x;
  float v0 = x[base + tid], v1 = x[base + 256 + tid];
  float sq = block_sum256(v0 * v0 + v1 * v1);
  float inv = 1.0f / fmaxf(sqrtf(sq), 1e-6f);
  x[base + tid] = v0 * inv;
  x[base + 256 + tid] = v1 * inv;
}

// fused gate + combine + LN2:
//   g   = alpha * sigmoid(x.Wg + bg) * (mean_h conf >= 0.35)
//   y   = x + g*proj   (fp32 back into proj, needed as MLP residual)
//   y2  = LN(y) -> bf16
__global__ __launch_bounds__(256) void combine_ln_kernel(const __hip_bfloat16* __restrict__ x,
                                                         float* __restrict__ proj,
                                                         const float* __restrict__ confh,
                                                         const float* __restrict__ Wg,
                                                         const float* __restrict__ bg,
                                                         const float* __restrict__ alpha_p,
                                                         const float* __restrict__ w,
                                                         const float* __restrict__ b,
                                                         __hip_bfloat16* __restrict__ y2) {
  int row = blockIdx.x;
  size_t base = (size_t)row * CDIM;
  int tid = threadIdx.x;
  float xv0 = __bfloat162float(x[base + tid]);
  float xv1 = __bfloat162float(x[base + 256 + tid]);
  float dot = block_sum256(xv0 * Wg[tid] + xv1 * Wg[256 + tid]);
  float csp = (tid < 8) ? confh[(size_t)tid * MROWS + row] : 0.0f;
  float cs = block_sum256(csp);
  float gate = 1.0f / (1.0f + expf(-(dot + bg[0])));
  float byp = (cs * 0.125f >= 0.35f) ? 1.0f : 0.0f;
  float gv = alpha_p[0] * gate * byp;

  float v0 = xv0 + gv * proj[base + tid];
  float v1 = xv1 + gv * proj[base + 256 + tid];
  proj[base + tid] = v0;
  proj[base + 256 + tid] = v1;
  float tot = block_sum256(v0 + v1);
  float mu = tot * (1.0f / 512.0f);
  float d0 = v0 - mu, d1 = v1 - mu;
  float sqs = block_sum256(d0 * d0 + d1 * d1);
  float rs = rsqrtf(sqs * (1.0f / 512.0f) + 1e-5f);
  y2[base + tid]       = __float2bfloat16(d0 * rs * w[tid]       + b[tid]);
  y2[base + 256 + tid] = __float2bfloat16(d1 * rs * w[256 + tid] + b[256 + tid]);
}

// ---------------- attention (EXACT round-3 version: 84 VGPR, 3 blocks/CU) ----------------
__global__ __launch_bounds__(256) void attn_kernel(const float* __restrict__ qn,
                                                   const float* __restrict__ kn,
                                                   const float* __restrict__ vf,
                                                   const float* __restrict__ pad,
                                                   const float* __restrict__ ls_p,
                                                   __hip_bfloat16* __restrict__ aligned,
                                                   float* __restrict__ confh) {
  __shared__ float kt[TTOK * 68];
  __shared__ float vt[TTOK * 68];
  __shared__ float qt[32 * 64];
  int tid = threadIdx.x;
  int lane = tid & 63, wid = tid >> 6;
  int blk = blockIdx.x;
  int nchunk = blk & 127;
  int bh = blk >> 7;
  int h = bh & 7, b = bh >> 3;

  for (int idx = tid; idx < TTOK * 64; idx += 256) {
    int t = idx >> 6, d = idx & 63;
    size_t src = ((size_t)(b * TTOK + t)) * CDIM + h * 64 + d;
    kt[t * 68 + d] = kn[src];
    vt[t * 68 + d] = vf[src];
  }
  for (int idx = tid; idx < 32 * 64; idx += 256) {
    int nl = idx >> 6, d = idx & 63;
    qt[idx] = qn[((size_t)(b * 4096 + nchunk * 32 + nl)) * CDIM + h * 64 + d];
  }
  __syncthreads();

  float ls = fminf(fmaxf(ls_p[0], -2.0f), 2.0f);
  float scale = expf(ls) * 0.125f;
  const float NEGINF = -__builtin_inff();
  float pv0 = pad[b * TTOK + lane];
  int t1ok = (lane + 64 < TTOK);
  float pv1 = t1ok ? pad[b * TTOK + lane + 64] : 1.0f;
  int t1 = t1ok ? lane + 64 : 0;

  for (int i = 0; i < 8; ++i) {
    int nl = wid * 8 + i;
    int n = nchunk * 32 + nl;
    size_t qbase = ((size_t)(b * 4096 + n)) * CDIM + h * 64;
    float s0 = 0.0f, s1 = 0.0f;
    const float4* qv4 = (const float4*)&qt[nl * 64];
    const float4* k0p = (const float4*)&kt[lane * 68];
    const float4* k1p = (const float4*)&kt[t1 * 68];
#pragma unroll
    for (int dg = 0; dg < 16; ++dg) {
      float4 qq = qv4[dg];
      float4 ka = k0p[dg];
      float4 kb = k1p[dg];
      s0 += qq.x * ka.x + qq.y * ka.y + qq.z * ka.z + qq.w * ka.w;
      s1 += qq.x * kb.x + qq.y * kb.y + qq.z * kb.z + qq.w * kb.w;
    }
    float v0 = (pv0 > 0.0f) ? NEGINF : s0 * scale;
    float v1 = (!t1ok || pv1 > 0.0f) ? NEGINF : s1 * scale;

    float m1 = wave_max(fmaxf(v0, v1));
    float a0 = 0.0f, a1 = 0.0f, conf_h = 0.0f;
    unsigned long long km0 = 0ull, km1 = 0ull;
    if (m1 != NEGINF) {
      int c1 = __popcll(__ballot(v0 >= m1)) + __popcll(__ballot(v1 >= m1));
      float thr;
      if (c1 >= 3) thr = m1;
      else {
        float m2 = wave_max(fmaxf(v0 < m1 ? v0 : NEGINF, v1 < m1 ? v1 : NEGINF));
        int c2 = __popcll(__ballot(v0 >= m2)) + __popcll(__ballot(v1 >= m2));
        if (c2 >= 3) thr = m2;
        else thr = wave_max(fmaxf(v0 < m2 ? v0 : NEGINF, v1 < m2 ? v1 : NEGINF));
      }
      float p0 = (v0 >= thr) ? expf(v0 - m1) : 0.0f;
      float p1 = (v1 >= thr) ? expf(v1 - m1) : 0.0f;
      float sum = wave_sum(p0 + p1);
      a0 = p0 / sum; a1 = p1 / sum;
      float sum2 = wave_sum(a0 + a1);
      float rden = 1.0f / fmaxf(sum2, 1e-6f);
      a0 *= rden; a1 *= rden;
      km0 = __ballot(a0 > 0.0f);
      km1 = __ballot(a1 > 0.0f);
      int cnt = __popcll(km0) + __popcll(km1);
      float maxp = wave_max(fmaxf(a0, a1));
      float es = wave_sum((a0 > 0.0f ? -a0 * logf(a0) : 0.0f) +
                          (a1 > 0.0f ? -a1 * logf(a1) : 0.0f));
      es += (float)(TTOK - cnt) * 1.8420680743952367e-7f;
      float teff = fmaxf((float)cnt, 2.0f);
      float ent = fmaxf(es / logf(teff), 0.0f);
      conf_h = fminf(fmaxf(maxp * (1.0f - ent), 0.0f), 1.0f);
    }
    if (lane == 0) confh[(size_t)h * MROWS + b * 4096 + n] = conf_h;

    float acc = 0.0f;
    unsigned long long m = km0;
    while (m) {
      int t = __builtin_ctzll(m);
      acc += __shfl(a0, t, 64) * vt[t * 68 + lane];
      m &= m - 1;
    }
    m = km1;
    while (m) {
      int t = __builtin_ctzll(m);
      acc += __shfl(a1, t, 64) * vt[(t + 64) * 68 + lane];
      m &= m - 1;
    }
    aligned[qbase + lane] = __float2bfloat16(acc);
  }
}

// ---------------- bf16 MFMA GEMM, m97-style global_load_lds staging ----------------
// C = A(MxK bf16) @ BT^T + bias; BT is NxK bf16. M%128==0, N%128==0, K%32==0.
// mode 0: out bf16; mode 1: out fp32; mode 2: out d_out (fp32 if *flag else bf16) at ooff.
__global__ __launch_bounds__(256) void mfma_gemm(const short* __restrict__ A,
                                                 const short* __restrict__ BT,
                                                 const float* __restrict__ bias,
                                                 void* __restrict__ outp,
                                                 int mode, size_t ooff,
                                                 const int* __restrict__ flag,
                                                 const float* __restrict__ resid,
                                                 int M, int N, int K, int act) {
  __shared__ short As[128 * 32];   // unpadded: required by global_load_lds lane mapping
  __shared__ short Bs[128 * 32];
  int tid = threadIdx.x;
  int lane = tid & 63, w = tid >> 6;
  int wr = w >> 1, wc = w & 1;
  int bm = blockIdx.y * 128, bn = blockIdx.x * 128;
  float4v acc[4][4];
#pragma unroll
  for (int i = 0; i < 4; ++i)
#pragma unroll
    for (int j = 0; j < 4; ++j) acc[i][j] = (float4v){0.f, 0.f, 0.f, 0.f};

  int srow = w * 32 + (lane >> 2);
  int scol = (lane & 3) * 8;
  const short* Ag0 = A + (size_t)(bm + srow) * K + scol;
  const short* Ag1 = A + (size_t)(bm + srow + 16) * K + scol;
  const short* Bg0 = BT + (size_t)(bn + srow) * K + scol;
  const short* Bg1 = BT + (size_t)(bn + srow + 16) * K + scol;
  short* Al0 = As + w * 1024;
  short* Al1 = As + w * 1024 + 512;
  short* Bl0 = Bs + w * 1024;
  short* Bl1 = Bs + w * 1024 + 512;

  int m0 = wr * 64 + (lane & 15);
  int n0 = wc * 64 + (lane & 15);
  int kg = (lane >> 4) * 8;

  for (int k0 = 0; k0 < K; k0 += 32) {
    __syncthreads();
    gload16(Ag0 + k0, Al0);
    gload16(Ag1 + k0, Al1);
    gload16(Bg0 + k0, Bl0);
    gload16(Bg1 + k0, Bl1);
    __syncthreads();
    short8 af[4], bf[4];
#pragma unroll
    for (int mi = 0; mi < 4; ++mi) af[mi] = *(const short8*)&As[(m0 + mi * 16) * 32 + kg];
#pragma unroll
    for (int ni = 0; ni < 4; ++ni) bf[ni] = *(const short8*)&Bs[(n0 + ni * 16) * 32 + kg];
#pragma unroll
    for (int mi = 0; mi < 4; ++mi)
#pragma unroll
      for (int ni = 0; ni < 4; ++ni)
        acc[mi][ni] = __builtin_amdgcn_mfma_f32_16x16x32_bf16(af[mi], bf[ni], acc[mi][ni], 0, 0, 0);
  }

  int outf32 = (mode == 2) ? *flag : 0;
#pragma unroll
  for (int mi = 0; mi < 4; ++mi) {
#pragma unroll
    for (int ni = 0; ni < 4; ++ni) {
#pragma unroll
      for (int r = 0; r < 4; ++r) {
        int gr = bm + wr * 64 + mi * 16 + (lane >> 4) * 4 + r;
        int gc = bn + wc * 64 + ni * 16 + (lane & 15);
        float v = acc[mi][ni][r] + bias[gc];
        if (act == 1) v = 0.5f * v * (1.0f + erff(v * 0.70710678118654752f));
        if (resid) v += resid[(size_t)gr * N + gc];
        size_t oi = (size_t)gr * N + gc;
        if (mode == 0)      ((__hip_bfloat16*)outp)[oi] = __float2bfloat16(v);
        else if (mode == 1) ((float*)outp)[oi] = v;
        else {
          if (outf32) ((float*)outp)[ooff + oi] = v;
          else        ((__hip_bfloat16*)outp)[ooff + oi] = __float2bfloat16(v);
        }
      }
    }
  }
}

// ---------------- fused k & v fp32 GEMM (raw inputs), M=616 ----------------
__global__ __launch_bounds__(256) void kv_gemm(const void* __restrict__ text,
                                               const void* __restrict__ Wk,
                                               const void* __restrict__ Wv,
                                               const float* __restrict__ bk,
                                               const float* __restrict__ bv,
                                               float* __restrict__ kf,
                                               float* __restrict__ vf,
                                               const int* __restrict__ flag) {
  __shared__ float As[16][128];
  __shared__ float Bs[16][128];
  int f = *flag;
  int isv = blockIdx.x >> 2;
  int bn = (blockIdx.x & 3) * 128;
  int bm = blockIdx.y * 128;
  const void* B = isv ? Wv : Wk;
  const float* bias = isv ? bv : bk;
  float* C = isv ? vf : kf;
  int tid = threadIdx.x;
  int tx = tid & 15, ty = tid >> 4;
  float acc[8][8] = {};
  for (int k0 = 0; k0 < 512; k0 += 16) {
#pragma unroll
    for (int r = 0; r < 8; ++r) {
      int idx = tid + r * 256;
      int row = idx >> 4, kk = idx & 15;
      int gr = bm + row;
      As[kk][row] = (gr < BTOK) ? ldin(text, (size_t)gr * 512 + k0 + kk, f) : 0.0f;
    }
#pragma unroll
    for (int r = 0; r < 8; ++r) {
      int idx = tid + r * 256;
      int kk = idx >> 7, col = idx & 127;
      Bs[kk][col] = ldin(B, (size_t)(k0 + kk) * 512 + bn + col, f);
    }
    __syncthreads();
#pragma unroll
    for (int kk = 0; kk < 16; ++kk) {
      float ra[8], rb[8];
#pragma unroll
      for (int i = 0; i < 8; ++i) ra[i] = As[kk][ty * 8 + i];
#pragma unroll
      for (int j = 0; j < 8; ++j) rb[j] = Bs[kk][tx * 8 + j];
#pragma unroll
      for (int i = 0; i < 8; ++i)
#pragma unroll
        for (int j = 0; j < 8; ++j) acc[i][j] += ra[i] * rb[j];
    }
    __syncthreads();
  }
#pragma unroll
  for (int i = 0; i < 8; ++i) {
    int gr = bm + ty * 8 + i;
    if (gr >= BTOK) continue;
#pragma unroll
    for (int j = 0; j < 8; ++j) {
      int gc = bn + tx * 8 + j;
      C[(size_t)gr * 512 + gc] = acc[i][j] + bias[gc];
    }
  }
}

extern "C" void kernel_launch(void* const* d_in, const int* in_sizes, int n_in,
                              void* d_out, int out_size, void* d_ws, size_t ws_size,
                              hipStream_t stream) {
  const void* visual = d_in[0];
  const void* text   = d_in[1];

  char* wsb = (char*)d_ws;
  size_t off = 0;
  auto alloc = [&](size_t bytes) { char* p = wsb + off; off += (bytes + 63) & ~63ull; return p; };

  float* qpy  = (float*)alloc((size_t)NTOK * 4);                    // q -> proj -> y
  __hip_bfloat16* xb2 = (__hip_bfloat16*)alloc((size_t)NTOK * 2);   // x -> y2
  __hip_bfloat16* alb = (__hip_bfloat16*)alloc((size_t)NTOK * 2);   // aligned
  __hip_bfloat16* h1b = (__hip_bfloat16*)alloc((size_t)16384 * 2048 * 2); // MLP hidden (half-M chunk)
  float* kfb  = (float*)alloc((size_t)BTOK * CDIM * 4);
  float* vfb  = (float*)alloc((size_t)BTOK * CDIM * 4);
  float* padb = (float*)alloc(BTOK * 4);
  float* confh = (float*)alloc((size_t)8 * MROWS * 4);
  float* n1w = (float*)alloc(512 * 4);  float* n1b = (float*)alloc(512 * 4);
  float* n2w = (float*)alloc(512 * 4);  float* n2b = (float*)alloc(512 * 4);
  float* bq  = (float*)alloc(512 * 4);  float* bk = (float*)alloc(512 * 4);
  float* bv  = (float*)alloc(512 * 4);  float* bo = (float*)alloc(512 * 4);
  float* Wgf = (float*)alloc(512 * 4);  float* bg = (float*)alloc(16);
  float* lsb = (float*)alloc(16);
  float* b1  = (float*)alloc(2048 * 4); float* b2 = (float*)alloc(512 * 4);
  float* alp = (float*)alloc(16);
  __hip_bfloat16* WqT = (__hip_bfloat16*)alloc((size_t)262144 * 2);
  __hip_bfloat16* WoT = (__hip_bfloat16*)alloc((size_t)262144 * 2);
  __hip_bfloat16* W1T = (__hip_bfloat16*)alloc((size_t)1048576 * 2);
  __hip_bfloat16* W2T = (__hip_bfloat16*)alloc((size_t)1048576 * 2);
  int* flag = (int*)alloc(16);

  detect_kernel<<<1, 256, 0, stream>>>((const unsigned int*)text, flag);

  PCTab tab = {{
    {d_in[2], n1w, 512}, {d_in[3], n1b, 512}, {d_in[4], n2w, 512}, {d_in[5], n2b, 512},
    {d_in[7], bq, 512},  {d_in[9], bk, 512},  {d_in[11], bv, 512}, {d_in[13], bo, 512},
    {d_in[14], Wgf, 512}, {d_in[15], bg, 1},  {d_in[16], lsb, 1},
    {d_in[18], b1, 2048}, {d_in[20], b2, 512}, {d_in[21], alp, 1},
  }};
  cvt_params_kernel<<<14, 256, 0, stream>>>(tab, flag);

  tcvt_kernel<<<dim3(16, 16), 256, 0, stream>>>(d_in[6],  WqT, 512, 512, flag);
  tcvt_kernel<<<dim3(16, 16), 256, 0, stream>>>(d_in[12], WoT, 512, 512, flag);
  tcvt_kernel<<<dim3(64, 16), 256, 0, stream>>>(d_in[17], W1T, 512, 2048, flag);
  tcvt_kernel<<<dim3(16, 64), 256, 0, stream>>>(d_in[19], W2T, 2048, 512, flag);

  pad_kernel<<<BTOK, 256, 0, stream>>>(text, padb, flag);
  ln_kernel<<<MROWS, 256, 0, stream>>>(visual, n1w, n1b, xb2, flag);

  mfma_gemm<<<dim3(4, 256), 256, 0, stream>>>((const short*)xb2, (const short*)WqT, bq,
                                              qpy, 1, 0, flag, nullptr, MROWS, 512, 512, 0);
  kv_gemm<<<dim3(8, 5), 256, 0, stream>>>(text, d_in[8], d_in[10], bk, bv, kfb, vfb, flag);
  rownorm_kernel<<<MROWS, 256, 0, stream>>>(qpy);
  rownorm_kernel<<<BTOK, 256, 0, stream>>>(kfb);

  attn_kernel<<<8 * 8 * 128, 256, 0, stream>>>(qpy, kfb, vfb, padb, lsb, alb, confh);

  mfma_gemm<<<dim3(4, 256), 256, 0, stream>>>((const short*)alb, (const short*)WoT, bo,
                                              qpy, 1, 0, flag, nullptr, MROWS, 512, 512, 0);
  combine_ln_kernel<<<MROWS, 256, 0, stream>>>(xb2, qpy, confh, Wgf, bg, alp, n2w, n2b, xb2);

  // MLP in 2 chunks of 16384 rows
  for (int c = 0; c < 2; ++c) {
    const short* ychunk = (const short*)(xb2 + (size_t)c * 16384 * CDIM);
    const float* yres   = qpy + (size_t)c * 16384 * CDIM;
    mfma_gemm<<<dim3(16, 128), 256, 0, stream>>>(ychunk, (const short*)W1T, b1,
                                                 h1b, 0, 0, flag, nullptr, 16384, 2048, 512, 1);
    mfma_gemm<<<dim3(4, 128), 256, 0, stream>>>((const short*)h1b, (const short*)W2T, b2,
                                                d_out, 2, (size_t)c * 16384 * CDIM, flag, yres,
                                                16384, 512, 2048, 0);
  }
}